// Round 8
// baseline (45.039 us; speedup 1.0000x reference)
//
#include <hip/hip_runtime.h>

#define HW 196
#define C  384
#define CF4 (C/4)          // 96 float4 per row
#define TK 98
#define SLICES 7
#define RPS 28             // rows per slice (7*28 = 196)

// ---------------- Kernel A: scores (pure streaming) ----------------
// grid = pairs*SLICES blocks of 256 threads; 8-lane group per row.
__global__ __launch_bounds__(256) void score_kernel(
    const float* __restrict__ token,
    const float* __restrict__ feature,
    float* __restrict__ scores)
{
    __shared__ float4 tokLds[CF4];

    const int tid   = threadIdx.x;
    const int bid   = blockIdx.x;
    const int pair  = bid / SLICES;
    const int slice = bid - pair * SLICES;
    const int g     = tid >> 3;        // group 0..31
    const int l8    = tid & 7;

    const float* tokp = token + (size_t)pair * C;
    const float4* f4base = (const float4*)(feature + (size_t)pair * (HW * C));

    // stage token (1.5 KB) then barrier; only this load is drained by the
    // barrier, so the feature burst below runs unfenced.
    if (tid < CF4) tokLds[tid] = ((const float4*)tokp)[tid];
    __syncthreads();

    const bool active = (g < RPS);
    const int  r = slice * RPS + g;    // 0..195
    const float4* fr = f4base + (size_t)r * CF4 + l8;

    float4 a[12];
    if (active) {
        #pragma unroll
        for (int k = 0; k < 12; ++k) a[k] = fr[8 * k];   // 12 independent 16B loads
        float4 acc = make_float4(0.f, 0.f, 0.f, 0.f);
        #pragma unroll
        for (int k = 0; k < 12; ++k) {
            float4 t = tokLds[l8 + 8 * k];               // LDS, hides under loads
            acc.x += a[k].x * t.x; acc.y += a[k].y * t.y;
            acc.z += a[k].z * t.z; acc.w += a[k].w * t.w;
        }
        float s = (acc.x + acc.y) + (acc.z + acc.w);
        s += __shfl_xor(s, 1, 64);
        s += __shfl_xor(s, 2, 64);
        s += __shfl_xor(s, 4, 64);
        if (l8 == 0)
            scores[(size_t)pair * HW + r] = s * 0.05103103630798288f; // *384^-0.5
    }
}

// ---------------- Kernel B: select + weighted sum ----------------
#define NT 512
#define NWAVE (NT/64)      // 8

__global__ __launch_bounds__(NT) void select_kernel(
    const float* __restrict__ feature,
    const float* __restrict__ scores_g,
    float* __restrict__ out)
{
    __shared__ float score[HW];
    __shared__ float selW[TK];
    __shared__ int   selIdx[TK];
    __shared__ float wsum[NWAVE];
    __shared__ int   rank2[2 * HW];
    __shared__ float part[NWAVE][C];
    __shared__ float s_max, s_winv;

    const int tid  = threadIdx.x;
    const int wave = tid >> 6;
    const int lane = tid & 63;
    const int pair = blockIdx.x;

    const float4* f4base = (const float4*)(feature + (size_t)pair * (HW * C));

    if (tid < HW) score[tid] = scores_g[(size_t)pair * HW + tid];
    __syncthreads();

    // threads 0..391: rank-count (2 per row, half-range each);
    // wave 7: max over scores.
    if (tid < 2 * HW) {
        const int i = tid >> 1, h = tid & 1;
        const float si = score[i];
        int cnt = 0;
        const int j0 = h * (HW / 2);
        for (int j = j0; j < j0 + HW / 2; ++j) {
            const float sj = score[j];
            cnt += (int)((sj > si) | ((sj == si) & (j < i)));
        }
        rank2[tid] = cnt;
    } else if (wave == NWAVE - 1) {
        float m = -3.4e38f;
        for (int i = lane; i < HW; i += 64) m = fmaxf(m, score[i]);
        #pragma unroll
        for (int off = 32; off > 0; off >>= 1)
            m = fmaxf(m, __shfl_xor(m, off, 64));
        if (lane == 0) s_max = m;
    }
    __syncthreads();

    // select + compact (softmax denom cancels: w = exp(s - max))
    float w = 0.f;
    if (tid < HW) {
        const int rank = rank2[2 * tid] + rank2[2 * tid + 1];
        if (rank < TK) {
            w = __expf(score[tid] - s_max);
            selIdx[rank] = tid;
            selW[rank]  = w;
        }
    }
    #pragma unroll
    for (int off = 32; off > 0; off >>= 1) w += __shfl_xor(w, off, 64);
    if (lane == 0) wsum[wave] = w;
    __syncthreads();
    if (tid == 0) {
        float s = 0.f;
        #pragma unroll
        for (int i = 0; i < NWAVE; ++i) s += wsum[i];
        s_winv = 1.f / s;
    }
    __syncthreads();

    // weighted sum over 98 selected rows (L3-warm from kernel A).
    float4 acc_a = make_float4(0.f, 0.f, 0.f, 0.f);
    float4 acc_b = make_float4(0.f, 0.f, 0.f, 0.f);
    #pragma unroll
    for (int j = 0; j < 12; ++j) {
        const int i = wave + NWAVE * j;          // 0..95
        const int   r   = selIdx[i];
        const float wgt = selW[i];
        const float4* f4 = f4base + (size_t)r * CF4;
        float4 aa = f4[lane];
        acc_a.x += wgt * aa.x; acc_a.y += wgt * aa.y;
        acc_a.z += wgt * aa.z; acc_a.w += wgt * aa.w;
        if (lane < 32) {
            float4 bb = f4[64 + lane];
            acc_b.x += wgt * bb.x; acc_b.y += wgt * bb.y;
            acc_b.z += wgt * bb.z; acc_b.w += wgt * bb.w;
        }
    }
    if (wave < TK - 96) {                         // rows 96, 97
        const int i = 96 + wave;
        const int   r   = selIdx[i];
        const float wgt = selW[i];
        const float4* f4 = f4base + (size_t)r * CF4;
        float4 aa = f4[lane];
        acc_a.x += wgt * aa.x; acc_a.y += wgt * aa.y;
        acc_a.z += wgt * aa.z; acc_a.w += wgt * aa.w;
        if (lane < 32) {
            float4 bb = f4[64 + lane];
            acc_b.x += wgt * bb.x; acc_b.y += wgt * bb.y;
            acc_b.z += wgt * bb.z; acc_b.w += wgt * bb.w;
        }
    }
    float4* pw = (float4*)&part[wave][0];
    pw[lane] = acc_a;
    if (lane < 32) pw[64 + lane] = acc_b;
    __syncthreads();

    if (tid < C) {
        float s = 0.f;
        #pragma unroll
        for (int wv = 0; wv < NWAVE; ++wv) s += part[wv][tid];
        out[(size_t)pair * C + tid] = s * s_winv;
    }
}

extern "C" void kernel_launch(void* const* d_in, const int* in_sizes, int n_in,
                              void* d_out, int out_size, void* d_ws, size_t ws_size,
                              hipStream_t stream) {
    const float* token   = (const float*)d_in[0];
    const float* feature = (const float*)d_in[1];
    float* out    = (float*)d_out;
    float* scores = (float*)d_ws;        // 512*196*4 B = 401 KB scratch
    const int pairs = in_sizes[0] / C;   // 8*16*4 = 512

    score_kernel<<<pairs * SLICES, 256, 0, stream>>>(token, feature, scores);
    select_kernel<<<pairs, NT, 0, stream>>>(feature, scores, out);
}